// Round 5
// baseline (469.592 us; speedup 1.0000x reference)
//
#include <hip/hip_runtime.h>
#include <math.h>

// ---------------- sizes ----------------
#define DD 256
#define KK 512
#define LL 64
#define BB 8
#define SS 16
#define F_LOG2PI 1.83787706641f
#define PER_I 16777216u   // i-stride in per-half eps flat index (64*16*64*256)

// ---------------- threefry2x32 (JAX-compatible) ----------------
struct U2 { unsigned x, y; };

__host__ __device__ constexpr U2 tf2x32(unsigned k0, unsigned k1, unsigned c0, unsigned c1) {
  unsigned ks2 = k0 ^ k1 ^ 0x1BD11BDAu;
  unsigned x0 = c0 + k0;
  unsigned x1 = c1 + k1;
#define TFR(r) { x0 += x1; x1 = (x1 << (r)) | (x1 >> (32 - (r))); x1 ^= x0; }
  TFR(13) TFR(15) TFR(26) TFR(6)   x0 += k1;  x1 += ks2 + 1u;
  TFR(17) TFR(29) TFR(16) TFR(24)  x0 += ks2; x1 += k0 + 2u;
  TFR(13) TFR(15) TFR(26) TFR(6)   x0 += k0;  x1 += k1 + 3u;
  TFR(17) TFR(29) TFR(16) TFR(24)  x0 += k1;  x1 += ks2 + 4u;
  TFR(13) TFR(15) TFR(26) TFR(6)   x0 += ks2; x1 += k0 + 5u;
#undef TFR
  return U2{x0, x1};
}

// Threefry with c0=0 and k1 pre-folded into the counter (x1 = c1 + k1).
// Returns x0 ^ x1 (the JAX partitionable 32-bit draw).
__device__ inline unsigned tf_fold(unsigned k0, unsigned k1, unsigned x1) {
  unsigned ks2 = k0 ^ k1 ^ 0x1BD11BDAu;
  unsigned x0 = k0;
#define TFR(r) { x0 += x1; x1 = (x1 << (r)) | (x1 >> (32 - (r))); x1 ^= x0; }
  TFR(13) TFR(15) TFR(26) TFR(6)   x0 += k1;  x1 += ks2 + 1u;
  TFR(17) TFR(29) TFR(16) TFR(24)  x0 += ks2; x1 += k0 + 2u;
  TFR(13) TFR(15) TFR(26) TFR(6)   x0 += k0;  x1 += k1 + 3u;
  TFR(17) TFR(29) TFR(16) TFR(24)  x0 += k1;  x1 += ks2 + 4u;
  TFR(13) TFR(15) TFR(26) TFR(6)   x0 += ks2; x1 += k0 + 5u;
#undef TFR
  return x0 ^ x1;
}

// bits -> p*u where eps = sqrt2 * p * u  (sqrt2 folded into caller's scale).
// Wave-uniform fast path when no lane needs the |u|>0.99665 branch (81% of
// waves). Arithmetic identical to the verified cndmask version per-lane.
__device__ inline float normal_pu(unsigned b) {
  float f = __uint_as_float((b >> 9) | 0x3f800000u) - 1.0f;   // [0,1)
  float u = fmaf(f, 2.0f, -0.99999994f);
  float w = -__logf(fmaf(-u, u, 1.0f));                       // -log(1-u*u)
  float p;
  if (__ballot(w >= 5.0f) == 0ull) {                          // wave-uniform
    float ww = w - 2.5f;
    p =            2.81022636e-08f;
    p = fmaf(p, ww, 3.43273939e-07f);
    p = fmaf(p, ww, -3.5233877e-06f);
    p = fmaf(p, ww, -4.39150654e-06f);
    p = fmaf(p, ww,  0.00021858087f);
    p = fmaf(p, ww, -0.00125372503f);
    p = fmaf(p, ww, -0.00417768164f);
    p = fmaf(p, ww,  0.246640727f);
    p = fmaf(p, ww,  1.50140941f);
  } else {
    bool s = w < 5.0f;
    float ww = s ? (w - 2.5f) : (__builtin_amdgcn_sqrtf(w) - 3.0f);
    p =          s ?  2.81022636e-08f : -0.000200214257f;
    p = fmaf(p, ww, s ?  3.43273939e-07f :  0.000100950558f);
    p = fmaf(p, ww, s ? -3.5233877e-06f  :  0.00134934322f);
    p = fmaf(p, ww, s ? -4.39150654e-06f : -0.00367342844f);
    p = fmaf(p, ww, s ?  0.00021858087f  :  0.00573950773f);
    p = fmaf(p, ww, s ? -0.00125372503f  : -0.0076224613f);
    p = fmaf(p, ww, s ? -0.00417768164f  :  0.00943887047f);
    p = fmaf(p, ww, s ?  0.246640727f    :  1.00167406f);
    p = fmaf(p, ww, s ?  1.50140941f     :  2.83297682f);
  }
  return p * u;
}

// ---------------- kernels ----------------

// Stable counting-sort of balanced labels (robust to int64 labels).
__global__ void k_sort(const int* __restrict__ labels, int* __restrict__ pos,
                       int* __restrict__ lmap) {
  __shared__ int lab[512];
  __shared__ int cnt[64];
  __shared__ int mode;
  int t = threadIdx.x;
  int v = labels[t];
  if (t < 64) cnt[t] = 0;
  if (t == 0) mode = 0;
  __syncthreads();
  atomicAdd(&cnt[v & 63], 1);
  __syncthreads();
  if (t < 64 && cnt[t] != 8) mode = 1;
  __syncthreads();
  if (mode) v = labels[2 * t];           // int64 little-endian low words
  lab[t] = v & 63;
  __syncthreads();
  int c = lab[t];
  int o = 0;
  for (int j = 0; j < t; ++j) o += (lab[j] == c);
  pos[c * 8 + o] = t;
  if (t < 64) lmap[t] = t;
}

// Prototype fusion per (half, class l).
__global__ void k_protos(const float* __restrict__ P, const float* __restrict__ he_p,
                         const int* __restrict__ pos, float* __restrict__ pm,
                         float* __restrict__ pe, float4* __restrict__ pq,
                         float* __restrict__ cl) {
  int hb = blockIdx.x;             // h*64 + l
  int h = hb >> 6, l = hb & 63;
  int d = threadIdx.x;
  float eps_var = expf(he_p[0]);
  int soff = h ? 0 : 4;            // support rows for this half
  float sinv = 0.f, sminv = 0.f;
#pragma unroll
  for (int j = 0; j < 4; ++j) {
    int row = pos[l * 8 + soff + j];
    float m = P[row * KK + d];
    float hh = P[row * KK + DD + d];
    float vv = eps_var + expf(hh);
    float iv = 1.0f / vv;
    sinv += iv; sminv += m * iv;
  }
  float nv = 1.0f / sinv;
  float nm = nv * sminv;
  float ev = eps_var + nv;         // exp(h_proto)
  pm[hb * DD + d] = nm;
  pe[hb * DD + d] = ev;
  float4 rec; rec.x = nm; rec.y = ev; rec.z = 1.0f / ev; rec.w = 0.0f;
  pq[(h * 256 + d) * 64 + l] = rec;
  float t = F_LOG2PI + __logf(ev);
  for (int off = 32; off; off >>= 1) t += __shfl_xor(t, off);
  __shared__ float red[4];
  int w = d >> 6, lane = d & 63;
  if (lane == 0) red[w] = t;
  __syncthreads();
  if (d == 0) cl[hb] = red[0] + red[1] + red[2] + red[3];
}

// lm[g,lq,lp] = logmls(query, proto)
__global__ void k_lm(const float* __restrict__ P, const int* __restrict__ pos,
                     const float* __restrict__ pm, const float* __restrict__ pe,
                     float* __restrict__ lm) {
  int bb = blockIdx.x;             // g*64 + lq
  int g = bb >> 6, lq = bb & 63;
  int h = g >> 2;
  int d = threadIdx.x;
  int row = pos[lq * 8 + g];
  float mq = P[row * KK + d];
  float vq = expf(P[row * KK + DD + d]);
  __shared__ float part[4][64];
  int w = d >> 6, lane = d & 63;
  for (int lp = 0; lp < 64; ++lp) {
    int pb = (h * 64 + lp) * DD + d;
    float mp = pm[pb], ev = pe[pb];
    float vs = vq + ev;
    float diff = mq - mp;
    float t = __logf(vs) + diff * diff * __builtin_amdgcn_rcpf(vs);
    for (int off = 32; off; off >>= 1) t += __shfl_xor(t, off);
    if (lane == 0) part[w][lp] = t;
  }
  __syncthreads();
  if (d < 64) {
    float s = part[0][d] + part[1][d] + part[2][d] + part[3][d];
    lm[bb * 64 + d] = -0.5f * (256.0f * F_LOG2PI + s);
  }
}

// Hot kernel: block=(h, lq, dchunk of 16). wave w = query i, lane = lp.
// 2 passes of 8 independent threefry chains (acc[8] keeps VGPR low).
// Partial d-sums atomically accumulated into accbuf[((g*64+lq)*16+s)*64+lp].
__global__ __launch_bounds__(256) void k_tl(const float* __restrict__ P,
    const int* __restrict__ pos, const float4* __restrict__ pq,
    float* __restrict__ accbuf) {
  constexpr U2 S1 = tf2x32(0u, 42u, 0u, 0u);  // foldlike split of key(42)
  constexpr U2 S2 = tf2x32(0u, 42u, 0u, 1u);
  int bb = blockIdx.x;             // h*1024 + lq*16 + chunk
  int h = bb >> 10;
  int lq = (bb >> 4) & 63;
  int chunk = bb & 15;
  int t = threadIdx.x;

  __shared__ float2 q[4 * 256];    // [i][d] = {m, exp(h)}
#pragma unroll
  for (int i = 0; i < 4; ++i) {
    int row = pos[lq * 8 + h * 4 + i];
    float2 rec;
    rec.x = P[row * KK + t];
    rec.y = expf(P[row * KK + DD + t]);
    q[i * 256 + t] = rec;
  }
  __syncthreads();

  int w = t >> 6, lane = t & 63;   // w = query i, lane = lp
  unsigned k0 = h ? S2.x : S1.x;
  unsigned k1 = h ? S2.y : S1.y;
  // eps flat idx (per half) = i*PER_I + lq*262144 + s*16384 + lp*256 + d
  // k1 folded into the counter base (threefry x1 init = c1 + k1).
  unsigned ebk = (unsigned)w * PER_I + (unsigned)lq * 262144u +
                 (unsigned)lane * 256u + (unsigned)chunk * 16u + k1;
  const float2* qd = &q[w * 256];
  const float4* pp = pq + (h * 256 + chunk * 16) * 64 + lane;
  int g = h * 4 + w;
  float* dst = accbuf + ((g * 64 + lq) * 16) * 64 + lane;

#pragma unroll 1
  for (int pass = 0; pass < 2; ++pass) {
    float acc[8];
#pragma unroll
    for (int s = 0; s < 8; ++s) acc[s] = 0.0f;
    unsigned pbase = (unsigned)pass * 8u * 16384u;
#pragma unroll 1
    for (int dd = 0; dd < 16; ++dd) {
      float4 pr = pp[dd * 64];           // {mp, ev, ivp, -} coalesced, L2-hot
      float2 qv = qd[chunk * 16 + dd];   // broadcast ds_read_b64
      float vs  = qv.y + pr.y;
      float ivs = __builtin_amdgcn_rcpf(vs);
      float evs = pr.y * ivs;            // ev/vs
      float sivp = __builtin_amdgcn_sqrtf(pr.z);
      float A = (qv.x - pr.x) * evs * sivp;                // sign irrelevant (squared)
      float S = __builtin_amdgcn_sqrtf(qv.y * evs) * sivp * 1.41421356f; // sqrt2 folded
      unsigned ebkd = ebk + pbase + (unsigned)dd;
#pragma unroll
      for (int s = 0; s < 8; ++s) {
        unsigned bits = tf_fold(k0, k1, ebkd + (unsigned)s * 16384u);
        float eps = normal_pu(bits);
        float diff = fmaf(S, eps, A);
        acc[s] = fmaf(diff, diff, acc[s]);
      }
    }
#pragma unroll
    for (int s = 0; s < 8; ++s) atomicAdd(dst + (pass * 8 + s) * 64, acc[s]);
  }
}

// Merged: per (g,lq): 16 lse over lp (wave w does s=w*4..w*4+3), then
// MC = logsumexp_s(-lse) - log S, then scatter out.
__global__ void k_final(const float* __restrict__ lm, const float* __restrict__ accbuf,
                        const float* __restrict__ cl, const int* __restrict__ pos,
                        const int* __restrict__ lmap, float* __restrict__ out) {
  int bb = blockIdx.x;             // g*64 + lq
  int g = bb >> 6, lq = bb & 63;
  int h = g >> 2;
  int t = threadIdx.x, w = t >> 6, lane = t & 63;
  __shared__ float lsebuf[16];
  float clv = cl[h * 64 + lane];
#pragma unroll
  for (int j = 0; j < 4; ++j) {
    int s = w * 4 + j;
    float tlv = -0.5f * (clv + accbuf[(bb * 16 + s) * 64 + lane]);
    float mx = tlv;
    for (int off = 32; off; off >>= 1) mx = fmaxf(mx, __shfl_xor(mx, off));
    float se = expf(tlv - mx);
    for (int off = 32; off; off >>= 1) se += __shfl_xor(se, off);
    if (lane == 0) lsebuf[s] = mx + __logf(se);
  }
  __syncthreads();
  if (t < 64) {
    float a = (t < 16) ? -lsebuf[t] : -INFINITY;
    float mx = a;
    for (int off = 32; off; off >>= 1) mx = fmaxf(mx, __shfl_xor(mx, off));
    float e = (t < 16) ? expf(a - mx) : 0.0f;
    for (int off = 32; off; off >>= 1) e += __shfl_xor(e, off);
    float mc = mx + __logf(e) - 2.7725887f;   // - log(16)
    int row = pos[lq * 8 + g];
    out[row * 64 + lmap[t]] = lm[bb * 64 + t] + mc;
  }
}

// ---------------- launch ----------------
extern "C" void kernel_launch(void* const* d_in, const int* in_sizes, int n_in,
                              void* d_out, int out_size, void* d_ws, size_t ws_size,
                              hipStream_t stream) {
  (void)in_sizes; (void)n_in; (void)out_size; (void)ws_size;
  const float* P      = (const float*)d_in[0];   // (512, 512) f32
  const float* he     = (const float*)d_in[1];   // scalar
  const int*   labels = (const int*)d_in[2];     // (512,) int
  float* out = (float*)d_out;                    // (512, 64) f32

  float* ws = (float*)d_ws;
  float* accbuf = ws;                   // [8][64][16][64] = 524288 floats (2 MB)
  float4* pq = (float4*)(ws + 524288);  // [2][256][64] float4 = 131072 floats
  float* pm  = ws + 655360;             // [2][64][256]
  float* pe  = ws + 688128;             // [2][64][256]
  float* cl  = ws + 720896;             // [2][64]
  float* lmw = ws + 721024;             // [8][64][64]
  int*   pos = (int*)(ws + 753792);     // [512]
  int*   lmp = pos + 512;               // [64]

  hipMemsetAsync(accbuf, 0, 524288 * sizeof(float), stream);
  hipLaunchKernelGGL(k_sort,   dim3(1),    dim3(512), 0, stream, labels, pos, lmp);
  hipLaunchKernelGGL(k_protos, dim3(128),  dim3(256), 0, stream, P, he, pos, pm, pe, pq, cl);
  hipLaunchKernelGGL(k_lm,     dim3(512),  dim3(256), 0, stream, P, pos, pm, pe, lmw);
  hipLaunchKernelGGL(k_tl,     dim3(2048), dim3(256), 0, stream, P, pos, pq, accbuf);
  hipLaunchKernelGGL(k_final,  dim3(512),  dim3(256), 0, stream, lmw, accbuf, cl, pos, lmp, out);
}